// Round 5
// baseline (209.009 us; speedup 1.0000x reference)
//
#include <hip/hip_runtime.h>

// GCN edge predictor, collapsed to scalar-per-node linear algebra:
//   u_i = x_i . w1c ;  v = A u + c1 ;  t = A v + c2 ;  out[g] = sum_g t + c0
//   A = D^-1/2 (Adj + I) D^-1/2
// R5: scatter staging fully in LDS (no per-thread arrays -> no scratch spill),
// wave-shuffle scans (2 barriers) replace Hillis-Steele (18 barriers).

#define RSHIFT 7
#define RNODES 128           // nodes per bucket
#define NB_MAX 1024          // max buckets (n <= 131072; src fits 17 bits)
#define NBLK 512             // tiles for count/scatter
#define STHREADS 512
#define STAGE_CAP 8192       // max edges per tile (E <= NBLK*STAGE_CAP)

// exclusive block scan of per-thread value `pair` over 512 threads.
// wsum must be __shared__ int[8]; on return wsum[7] = block total.
__device__ __forceinline__ int block_scan_pair(int pair, int tid, int* wsum) {
    int lane = tid & 63, wave = tid >> 6;
    int incl = pair;
    #pragma unroll
    for (int off = 1; off < 64; off <<= 1) {
        int a = __shfl_up(incl, off, 64);
        if (lane >= off) incl += a;
    }
    if (lane == 63) wsum[wave] = incl;
    __syncthreads();
    if (tid < 64) {
        int v = (lane < 8) ? wsum[lane] : 0;
        #pragma unroll
        for (int off = 1; off < 8; off <<= 1) {
            int a = __shfl_up(v, off, 64);
            if (lane >= off) v += a;
        }
        if (lane < 8) wsum[lane] = v;
    }
    __syncthreads();
    int wexcl = wave ? wsum[wave - 1] : 0;
    return wexcl + incl - pair;
}

__global__ void collapse_weights_k(
    const float* __restrict__ W1, const float* __restrict__ b1,
    const float* __restrict__ W2, const float* __restrict__ b2,
    const float* __restrict__ Wf1, const float* __restrict__ bf1,
    const float* __restrict__ Wf2, const float* __restrict__ bf2,
    const float* __restrict__ Wf3, const float* __restrict__ bf3,
    const float* __restrict__ Wo, const float* __restrict__ bo,
    float* __restrict__ w1c, float* __restrict__ sc)
{
    __shared__ float wo[10], w3[20], w2[30], w1[50], w2c[60];
    const int t = threadIdx.x;  // 64 threads
    if (t < 10) wo[t] = Wo[t];
    __syncthreads();
    if (t < 20) { float s = 0.f; for (int j = 0; j < 10; ++j) s += Wf3[t*10+j]*wo[j]; w3[t] = s; }
    __syncthreads();
    if (t < 30) { float s = 0.f; for (int j = 0; j < 20; ++j) s += Wf2[t*20+j]*w3[j]; w2[t] = s; }
    __syncthreads();
    if (t < 50) { float s = 0.f; for (int j = 0; j < 30; ++j) s += Wf1[t*30+j]*w2[j]; w1[t] = s; }
    __syncthreads();
    if (t < 60) { float s = 0.f; for (int j = 0; j < 50; ++j) s += W2[t*50+j]*w1[j]; w2c[t] = s; }
    __syncthreads();
    { float s = 0.f; for (int j = 0; j < 60; ++j) s += W1[t*60+j]*w2c[j]; w1c[t] = s; }
    if (t == 0) {
        float c1 = 0.f; for (int j = 0; j < 60; ++j) c1 += b1[j]*w2c[j];
        float c2 = 0.f; for (int j = 0; j < 50; ++j) c2 += b2[j]*w1[j];
        float c0 = bo[0];
        for (int j = 0; j < 30; ++j) c0 += bf1[j]*w2[j];
        for (int j = 0; j < 20; ++j) c0 += bf2[j]*w3[j];
        for (int j = 0; j < 10; ++j) c0 += bf3[j]*wo[j];
        sc[0] = c1; sc[1] = c2; sc[2] = c0;
    }
}

// 4 nodes per wave, float4 per 16-lane group: u[i] = x[i,:] . w1c
__global__ void node_u_k(const float* __restrict__ x, const float* __restrict__ w1c,
                         float* __restrict__ u, int n) {
    int tid = blockIdx.x * blockDim.x + threadIdx.x;
    int wave = tid >> 6;
    int lane = threadIdx.x & 63;
    int node = wave * 4 + (lane >> 4);
    int sub = lane & 15;
    if (node >= n) return;
    float4 xv = *reinterpret_cast<const float4*>(x + (size_t)node * 64 + sub * 4);
    float4 wv = *reinterpret_cast<const float4*>(w1c + sub * 4);
    float val = xv.x * wv.x + xv.y * wv.y + xv.z * wv.z + xv.w * wv.w;
    val += __shfl_down(val, 8, 16);
    val += __shfl_down(val, 4, 16);
    val += __shfl_down(val, 2, 16);
    val += __shfl_down(val, 1, 16);
    if (sub == 0) u[node] = val;
}

// per-tile bucket histogram -> cnt_bm[tile*nb + b]
__global__ void __launch_bounds__(STHREADS) bin_count_k(
    const int* __restrict__ dst, int E, int chunk, int nb, int* __restrict__ cnt_bm) {
    __shared__ int hist[NB_MAX];
    int tid = threadIdx.x;
    hist[tid] = 0; hist[tid + 512] = 0;
    __syncthreads();
    int e0 = blockIdx.x * chunk;
    int e1 = e0 + chunk; if (e1 > E) e1 = E;
    for (int i = e0 + tid * 4; i < e1; i += STHREADS * 4) {
        if (i + 3 < e1) {
            int4 d = *reinterpret_cast<const int4*>(dst + i);
            atomicAdd(&hist[d.x >> RSHIFT], 1);
            atomicAdd(&hist[d.y >> RSHIFT], 1);
            atomicAdd(&hist[d.z >> RSHIFT], 1);
            atomicAdd(&hist[d.w >> RSHIFT], 1);
        } else {
            for (int k = i; k < e1; ++k) atomicAdd(&hist[dst[k] >> RSHIFT], 1);
        }
    }
    __syncthreads();
    for (int b = tid; b < nb; b += STHREADS)
        cnt_bm[(size_t)blockIdx.x * nb + b] = hist[b];
}

// one block per bucket: exclusive scan over NBLK tiles -> offs[b*NBLK+k], total[b]
__global__ void __launch_bounds__(STHREADS) scanA_k(
    const int* __restrict__ cnt_bm, int nb, int* __restrict__ offs, int* __restrict__ total) {
    __shared__ int wsum[8];
    int k = threadIdx.x, b = blockIdx.x;
    int v = cnt_bm[(size_t)k * nb + b];
    int excl = block_scan_pair(v, k, wsum);
    offs[(size_t)b * NBLK + k] = excl;
    if (k == 0) total[b] = wsum[7];
}

// scan bucket totals (4-aligned bases) -> base[b], endp[b]; also out[g] = c0
__global__ void __launch_bounds__(STHREADS) scanB_k(
    const int* __restrict__ total, int nb, int* __restrict__ base, int* __restrict__ endp,
    const float* __restrict__ sc, float* __restrict__ out, int G) {
    __shared__ int wsum[8];
    int t = threadIdx.x;
    if (t < G) out[t] = sc[2];
    int b0 = 2 * t, b1 = 2 * t + 1;
    int t0 = (b0 < nb) ? total[b0] : 0;
    int t1 = (b1 < nb) ? total[b1] : 0;
    int a0 = (t0 + 3) & ~3, a1 = (t1 + 3) & ~3;
    int excl = block_scan_pair(a0 + a1, t, wsum);
    if (b0 < nb) { base[b0] = excl; endp[b0] = excl + t0; }
    if (b1 < nb) { base[b1] = excl + a0; endp[b1] = excl + a0 + t1; }
}

// block-local counting sort of a tile (all staging in LDS), dense flush
__global__ void __launch_bounds__(STHREADS) bin_scatter_k(
    const int* __restrict__ src, const int* __restrict__ dst,
    int E, int chunk, int nb,
    const int* __restrict__ base, const int* __restrict__ offs,
    unsigned int* __restrict__ binned) {
    __shared__ unsigned int raw[STAGE_CAP];      // packed edge, load order
    __shared__ unsigned int rb[STAGE_CAP];       // (bucket<<16) | rank
    __shared__ unsigned int sorted_[STAGE_CAP];  // bucket-sorted packed edges
    __shared__ unsigned short bofs[STAGE_CAP];   // bucket of sorted slot
    __shared__ int hist[NB_MAX];
    __shared__ int tbase[NB_MAX];
    __shared__ int adj[NB_MAX];
    __shared__ int wsum[8];
    const int tid = threadIdx.x;
    hist[tid] = 0; hist[tid + 512] = 0;
    __syncthreads();
    int e0 = blockIdx.x * chunk;
    int e1 = e0 + chunk; if (e1 > E) e1 = E;
    int tcount = e1 - e0;
    for (int i = e0 + tid * 4; i < e1; i += STHREADS * 4) {
        if (i + 3 < e1) {
            int4 s4 = *reinterpret_cast<const int4*>(src + i);
            int4 d4 = *reinterpret_cast<const int4*>(dst + i);
            int li = i - e0;
            int b, r;
            b = d4.x >> RSHIFT; r = atomicAdd(&hist[b], 1);
            raw[li+0] = (unsigned)s4.x | ((unsigned)(d4.x & (RNODES-1)) << 17);
            rb[li+0] = ((unsigned)b << 16) | (unsigned)r;
            b = d4.y >> RSHIFT; r = atomicAdd(&hist[b], 1);
            raw[li+1] = (unsigned)s4.y | ((unsigned)(d4.y & (RNODES-1)) << 17);
            rb[li+1] = ((unsigned)b << 16) | (unsigned)r;
            b = d4.z >> RSHIFT; r = atomicAdd(&hist[b], 1);
            raw[li+2] = (unsigned)s4.z | ((unsigned)(d4.z & (RNODES-1)) << 17);
            rb[li+2] = ((unsigned)b << 16) | (unsigned)r;
            b = d4.w >> RSHIFT; r = atomicAdd(&hist[b], 1);
            raw[li+3] = (unsigned)s4.w | ((unsigned)(d4.w & (RNODES-1)) << 17);
            rb[li+3] = ((unsigned)b << 16) | (unsigned)r;
        } else {
            for (int k = i; k < e1; ++k) {
                int s = src[k], d = dst[k];
                int b = d >> RSHIFT;
                int r = atomicAdd(&hist[b], 1);
                raw[k - e0] = (unsigned)s | ((unsigned)(d & (RNODES-1)) << 17);
                rb[k - e0] = ((unsigned)b << 16) | (unsigned)r;
            }
        }
    }
    __syncthreads();
    // exclusive scan of hist[0..1023], 2 slots per thread (wave shuffles)
    int h0 = hist[2*tid], h1 = hist[2*tid+1];
    int excl = block_scan_pair(h0 + h1, tid, wsum);
    tbase[2*tid] = excl;
    tbase[2*tid+1] = excl + h0;
    __syncthreads();
    {
        int b0 = 2*tid, b1 = 2*tid + 1;
        if (b0 < nb) adj[b0] = base[b0] + offs[(size_t)b0 * NBLK + blockIdx.x] - tbase[b0];
        if (b1 < nb) adj[b1] = base[b1] + offs[(size_t)b1 * NBLK + blockIdx.x] - tbase[b1];
    }
    __syncthreads();
    // rank-place into bucket-sorted LDS
    for (int li = tid; li < tcount; li += STHREADS) {
        unsigned v = rb[li];
        int b = (int)(v >> 16);
        int slot = tbase[b] + (int)(v & 0xFFFF);
        sorted_[slot] = raw[li];
        bofs[slot] = (unsigned short)b;
    }
    __syncthreads();
    // dense flush (consecutive LDS slots -> mostly-consecutive global slots)
    for (int s = tid; s < tcount; s += STHREADS) {
        binned[adj[bofs[s]] + s] = sorted_[s];
    }
}

// in-degree per node -> dinv = rsqrt(deg+1); w = dinv * u
__global__ void __launch_bounds__(STHREADS) degree_k(
    const unsigned int* __restrict__ binned, const int* __restrict__ base,
    const int* __restrict__ endp, const float* __restrict__ u,
    float* __restrict__ dinv, float* __restrict__ w, int n) {
    __shared__ int cnt[RNODES];
    int tid = threadIdx.x, b = blockIdx.x;
    if (tid < RNODES) cnt[tid] = 0;
    __syncthreads();
    int s0 = base[b], s1 = endp[b];
    int nvec = (s1 - s0) >> 2;
    for (int k = tid; k < nvec; k += blockDim.x) {
        uint4 p = *reinterpret_cast<const uint4*>(binned + s0 + 4 * k);
        atomicAdd(&cnt[p.x >> 17], 1);
        atomicAdd(&cnt[p.y >> 17], 1);
        atomicAdd(&cnt[p.z >> 17], 1);
        atomicAdd(&cnt[p.w >> 17], 1);
    }
    int i = s0 + 4 * nvec + tid;
    if (i < s1) atomicAdd(&cnt[binned[i] >> 17], 1);
    __syncthreads();
    int g = (b << RSHIFT) + tid;
    if (tid < RNODES && g < n) {
        float d = rsqrtf((float)(cnt[tid] + 1));
        dinv[g] = d;
        w[g] = d * u[g];
    }
}

// v = c1 + dinv*(sum of w[src]) + dinv^2*u ; wb = dinv*v
__global__ void __launch_bounds__(STHREADS) conv_mid_k(
    const unsigned int* __restrict__ binned, const int* __restrict__ base,
    const int* __restrict__ endp,
    const float* __restrict__ w, const float* __restrict__ dinv,
    const float* __restrict__ u, const float* __restrict__ sc,
    float* __restrict__ v, float* __restrict__ wb, int n) {
    __shared__ float acc[RNODES];
    int tid = threadIdx.x, b = blockIdx.x;
    if (tid < RNODES) acc[tid] = 0.f;
    __syncthreads();
    int s0 = base[b], s1 = endp[b];
    int nvec = (s1 - s0) >> 2;
    for (int k = tid; k < nvec; k += blockDim.x) {
        uint4 p = *reinterpret_cast<const uint4*>(binned + s0 + 4 * k);
        float wx = w[p.x & 0x1FFFF];
        float wy = w[p.y & 0x1FFFF];
        float wz = w[p.z & 0x1FFFF];
        float ww = w[p.w & 0x1FFFF];
        atomicAdd(&acc[p.x >> 17], wx);
        atomicAdd(&acc[p.y >> 17], wy);
        atomicAdd(&acc[p.z >> 17], wz);
        atomicAdd(&acc[p.w >> 17], ww);
    }
    int i = s0 + 4 * nvec + tid;
    if (i < s1) { unsigned p = binned[i]; atomicAdd(&acc[p >> 17], w[p & 0x1FFFF]); }
    __syncthreads();
    int g = (b << RSHIFT) + tid;
    if (tid < RNODES && g < n) {
        float di = dinv[g];
        float val = sc[0] + di * acc[tid] + di * di * u[g];
        v[g] = val;
        wb[g] = di * val;
    }
}

// t = c2 + dinv*sum + dinv^2*v, then segmented pool by sorted batch id
__global__ void __launch_bounds__(STHREADS) conv_final_k(
    const unsigned int* __restrict__ binned, const int* __restrict__ base,
    const int* __restrict__ endp,
    const float* __restrict__ wb, const float* __restrict__ dinv,
    const float* __restrict__ v, const float* __restrict__ sc,
    const int* __restrict__ batch, float* __restrict__ out, int n) {
    __shared__ float acc[RNODES];
    __shared__ float tbuf[RNODES];
    __shared__ int gbuf[RNODES];
    int tid = threadIdx.x, b = blockIdx.x;
    if (tid < RNODES) acc[tid] = 0.f;
    __syncthreads();
    int s0 = base[b], s1 = endp[b];
    int nvec = (s1 - s0) >> 2;
    for (int k = tid; k < nvec; k += blockDim.x) {
        uint4 p = *reinterpret_cast<const uint4*>(binned + s0 + 4 * k);
        float wx = wb[p.x & 0x1FFFF];
        float wy = wb[p.y & 0x1FFFF];
        float wz = wb[p.z & 0x1FFFF];
        float ww = wb[p.w & 0x1FFFF];
        atomicAdd(&acc[p.x >> 17], wx);
        atomicAdd(&acc[p.y >> 17], wy);
        atomicAdd(&acc[p.z >> 17], wz);
        atomicAdd(&acc[p.w >> 17], ww);
    }
    int i = s0 + 4 * nvec + tid;
    if (i < s1) { unsigned p = binned[i]; atomicAdd(&acc[p >> 17], wb[p & 0x1FFFF]); }
    __syncthreads();
    int g = (b << RSHIFT) + tid;
    float tval = 0.f; int gid = -1;
    if (tid < RNODES && g < n) {
        float di = dinv[g];
        tval = sc[1] + di * acc[tid] + di * di * v[g];
        gid = batch[g];
    }
    if (tid < RNODES) { tbuf[tid] = tval; gbuf[tid] = gid; }
    __syncthreads();
    if (tid < RNODES && g < n) {
        bool head = (tid == 0) || (gbuf[tid - 1] != gid);
        if (head) {
            float s = 0.f;
            int i2 = tid;
            while (i2 < RNODES && gbuf[i2] == gid) { s += tbuf[i2]; ++i2; }
            atomicAdd(&out[gid], s);
        }
    }
}

extern "C" void kernel_launch(void* const* d_in, const int* in_sizes, int n_in,
                              void* d_out, int out_size, void* d_ws, size_t ws_size,
                              hipStream_t stream)
{
    const float* x    = (const float*)d_in[0];
    const int*   ei   = (const int*)d_in[1];
    const int*   batch= (const int*)d_in[2];
    const float* W1   = (const float*)d_in[3];
    const float* b1   = (const float*)d_in[4];
    const float* W2   = (const float*)d_in[5];
    const float* b2   = (const float*)d_in[6];
    const float* Wf1  = (const float*)d_in[7];
    const float* bf1  = (const float*)d_in[8];
    const float* Wf2  = (const float*)d_in[9];
    const float* bf2  = (const float*)d_in[10];
    const float* Wf3  = (const float*)d_in[11];
    const float* bf3  = (const float*)d_in[12];
    const float* Wo   = (const float*)d_in[13];
    const float* bo   = (const float*)d_in[14];
    float* out = (float*)d_out;

    const int n = in_sizes[0] / 64;
    const int E = in_sizes[1] / 2;
    const int G = out_size;
    const int* src = ei;
    const int* dst = ei + E;
    const int nb = (n + RNODES - 1) >> RSHIFT;

    float* ws_f = (float*)d_ws;
    int*   ws_i = (int*)d_ws;
    float* w1c    = ws_f;                    // 64
    float* sc     = ws_f + 64;               // 3 (+pad to 128)
    int*   basep  = ws_i + 128;              // NB_MAX
    int*   endp   = ws_i + 128 + NB_MAX;     // NB_MAX
    int*   total  = ws_i + 128 + 2*NB_MAX;   // NB_MAX
    int*   offs   = ws_i + 128 + 3*NB_MAX;   // nb*NBLK
    size_t off_u  = 128 + 3*(size_t)NB_MAX + (size_t)nb * NBLK;
    off_u = (off_u + 3) & ~(size_t)3;
    float* u      = ws_f + off_u;            // n
    float* dinv   = u + n;                   // n
    float* w      = dinv + n;                // n
    float* v      = w + n;                   // n
    float* wb     = v + n;                   // n
    size_t off_b  = off_u + 5*(size_t)n;
    off_b = (off_b + 3) & ~(size_t)3;
    unsigned int* binned = (unsigned int*)(ws_f + off_b);   // E + 4*nb
    int* cnt_bm = (int*)binned;   // aliased: consumed by scanA before scatter writes

    int chunk = (E + NBLK - 1) / NBLK;
    chunk = (chunk + 3) & ~3;

    hipLaunchKernelGGL(collapse_weights_k, dim3(1), dim3(64), 0, stream,
                       W1, b1, W2, b2, Wf1, bf1, Wf2, bf2, Wf3, bf3, Wo, bo, w1c, sc);
    hipLaunchKernelGGL(node_u_k, dim3((n / 4 * 64 + 255) / 256 + 1), dim3(256), 0, stream,
                       x, w1c, u, n);
    hipLaunchKernelGGL(bin_count_k, dim3(NBLK), dim3(STHREADS), 0, stream,
                       dst, E, chunk, nb, cnt_bm);
    hipLaunchKernelGGL(scanA_k, dim3(nb), dim3(STHREADS), 0, stream,
                       cnt_bm, nb, offs, total);
    hipLaunchKernelGGL(scanB_k, dim3(1), dim3(STHREADS), 0, stream,
                       total, nb, basep, endp, sc, out, G);
    hipLaunchKernelGGL(bin_scatter_k, dim3(NBLK), dim3(STHREADS), 0, stream,
                       src, dst, E, chunk, nb, basep, offs, binned);
    hipLaunchKernelGGL(degree_k, dim3(nb), dim3(STHREADS), 0, stream,
                       binned, basep, endp, u, dinv, w, n);
    hipLaunchKernelGGL(conv_mid_k, dim3(nb), dim3(STHREADS), 0, stream,
                       binned, basep, endp, w, dinv, u, sc, v, wb, n);
    hipLaunchKernelGGL(conv_final_k, dim3(nb), dim3(STHREADS), 0, stream,
                       binned, basep, endp, wb, dinv, v, sc, batch, out, n);
}